// Round 10
// baseline (1047.008 us; speedup 1.0000x reference)
//
#include <hip/hip_runtime.h>
#include <hip/hip_bf16.h>

#define NN 50000
#define NE 800000
#define HH 128
#define PIN_ 16
#define PEIN_ 8
#define POUT_ 8
#define LAYERS_ 4
#define EPSM 1e-7f

typedef __bf16 bf16x8 __attribute__((ext_vector_type(8)));
typedef float f32x4 __attribute__((ext_vector_type(4)));
typedef float f32x2 __attribute__((ext_vector_type(2)));

__device__ inline unsigned short f2bf(float f) {
  unsigned int u = __float_as_uint(f);
  u += 0x7FFFu + ((u >> 16) & 1u);  // RNE
  return (unsigned short)(u >> 16);
}
__device__ inline unsigned int packbf(float lo, float hi) {
  return (unsigned int)f2bf(lo) | ((unsigned int)f2bf(hi) << 16);
}
__device__ inline float bflo(unsigned int p) { return __uint_as_float(p << 16); }
__device__ inline float bfhi(unsigned int p) { return __uint_as_float(p & 0xFFFF0000u); }
__device__ inline f32x2 unpk(unsigned int p) {
  return (f32x2){__uint_as_float(p << 16), __uint_as_float(p & 0xFFFF0000u)};
}

// ---------------- CSR build ----------------

__global__ void count_deg_kernel(const int* __restrict__ dst, int* __restrict__ deg) {
  int i = blockIdx.x * blockDim.x + threadIdx.x;
  if (i < NE) atomicAdd(&deg[dst[i]], 1);
}

__global__ __launch_bounds__(1024) void scan_kernel(const int* __restrict__ deg,
                                                    int* __restrict__ row_ptr,
                                                    int* __restrict__ cursor, int n) {
  __shared__ int wsum[16];
  __shared__ int carry_s;
  int t = threadIdx.x;
  int lane = t & 63, wv = t >> 6;
  if (t == 0) carry_s = 0;
  __syncthreads();
  for (int base = 0; base < n; base += 1024) {
    int i = base + t;
    int v = (i < n) ? deg[i] : 0;
    int x = v;
#pragma unroll
    for (int off = 1; off < 64; off <<= 1) {
      int y = __shfl_up(x, off, 64);
      if (lane >= off) x += y;
    }
    if (lane == 63) wsum[wv] = x;
    __syncthreads();
    if (wv == 0 && lane < 16) {
      int s = wsum[lane];
#pragma unroll
      for (int off = 1; off < 16; off <<= 1) {
        int y = __shfl_up(s, off, 16);
        if (lane >= off) s += y;
      }
      wsum[lane] = s;
    }
    __syncthreads();
    int waveExcl = (wv > 0) ? wsum[wv - 1] : 0;
    int carry = carry_s;
    int excl = carry + waveExcl + x - v;
    if (i < n) { row_ptr[i] = excl; cursor[i] = excl; }
    __syncthreads();
    if (t == 1023) carry_s = carry + wsum[15];
    __syncthreads();
  }
  if (t == 0) row_ptr[n] = carry_s;
}

__global__ void scatter_kernel(const int* __restrict__ src, const int* __restrict__ dst,
                               int* __restrict__ cursor, int2* __restrict__ csr,
                               int* __restrict__ srcs) {
  int i = blockIdx.x * blockDim.x + threadIdx.x;
  if (i < NE) {
    int d = dst[i];
    int pos = atomicAdd(&cursor[d], 1);
    csr[pos] = make_int2(src[i], i);
    srcs[pos] = src[i];
  }
}

// ---------------- edge encoder precompute (first `cap` CSR slots) ----------------

__global__ __launch_bounds__(256) void edge_enc_kernel(
    const int2* __restrict__ csr, const float* __restrict__ edge_attr,
    const float* __restrict__ edge_W, const float* __restrict__ edge_b,
    int cap, unsigned int* __restrict__ epk) {
  int wv = threadIdx.x >> 6, lane = threadIdx.x & 63;
  int p = blockIdx.x * 4 + wv;
  if (p >= cap) return;
  int2 se = csr[p];
  const float4* ea = (const float4*)(edge_attr + (size_t)se.y * PEIN_);
  float4 A = ea[0], B = ea[1];
  float acc0 = edge_b[lane], acc1 = edge_b[lane + 64];
#pragma unroll
  for (int k = 0; k < PEIN_; ++k) {
    float av = (k < 4) ? ((k == 0) ? A.x : (k == 1) ? A.y : (k == 2) ? A.z : A.w)
                       : ((k == 4) ? B.x : (k == 5) ? B.y : (k == 6) ? B.z : B.w);
    acc0 = fmaf(av, edge_W[k * HH + lane], acc0);
    acc1 = fmaf(av, edge_W[k * HH + lane + 64], acc1);
  }
  float e0 = __builtin_amdgcn_rcpf(1.f + __expf(-acc0));
  float e1 = __builtin_amdgcn_rcpf(1.f + __expf(-acc1));
  epk[(size_t)p * 64 + lane] = packbf(e0, e1);
}

// ---------------- hybrid softmax aggregation ----------------

__device__ __forceinline__ void estep(unsigned int ep, unsigned int zp, float t,
                                      f32x2& d, f32x2& a) {
  f32x2 msg = unpk(zp) + unpk(ep);
  msg = __builtin_elementwise_max(msg, (f32x2){0.f, 0.f});
  msg += (f32x2){EPSM, EPSM};
  f32x2 s = msg * t;
  f32x2 w;
  w.x = __expf(s.x);
  w.y = __expf(s.y);
  d += w;
  a = __builtin_elementwise_fma(msg, w, a);
}

__device__ __forceinline__ void edge_step(float4 A, float4 B, unsigned int zp,
                                          const f32x2* ew, f32x2 eb, float t,
                                          f32x2& d, f32x2& a) {
  f32x2 acc = eb;
  acc = __builtin_elementwise_fma((f32x2){A.x, A.x}, ew[0], acc);
  acc = __builtin_elementwise_fma((f32x2){A.y, A.y}, ew[1], acc);
  acc = __builtin_elementwise_fma((f32x2){A.z, A.z}, ew[2], acc);
  acc = __builtin_elementwise_fma((f32x2){A.w, A.w}, ew[3], acc);
  acc = __builtin_elementwise_fma((f32x2){B.x, B.x}, ew[4], acc);
  acc = __builtin_elementwise_fma((f32x2){B.y, B.y}, ew[5], acc);
  acc = __builtin_elementwise_fma((f32x2){B.z, B.z}, ew[6], acc);
  acc = __builtin_elementwise_fma((f32x2){B.w, B.w}, ew[7], acc);
  f32x2 e;
  e.x = __builtin_amdgcn_rcpf(1.f + __expf(-acc.x));
  e.y = __builtin_amdgcn_rcpf(1.f + __expf(-acc.y));
  f32x2 msg = unpk(zp) + e;
  msg = __builtin_elementwise_max(msg, (f32x2){0.f, 0.f});
  msg += (f32x2){EPSM, EPSM};
  f32x2 s = msg * t;
  f32x2 w;
  w.x = __expf(s.x);
  w.y = __expf(s.y);
  d += w;
  a = __builtin_elementwise_fma(msg, w, a);
}

__global__ __launch_bounds__(256) void aggregate_hyb_kernel(
    const int* __restrict__ row_ptr, const int2* __restrict__ csr,
    const int* __restrict__ srcs, const unsigned int* __restrict__ epk, int cap,
    const float* __restrict__ edge_attr, const float* __restrict__ edge_W,
    const float* __restrict__ edge_b, const unsigned int* __restrict__ zpk,
    const float* __restrict__ t_all, int layer, unsigned int* __restrict__ upk) {
  int wv = threadIdx.x >> 6, lane = threadIdx.x & 63;
  int n = blockIdx.x * 4 + wv;
  if (n >= NN) return;
  float t = t_all[layer];
  int beg = row_ptr[n], end = row_ptr[n + 1];
  unsigned int zs = zpk[(size_t)n * 64 + lane];
  f32x2 d = {0.f, 0.f}, a = {0.f, 0.f};

  if (end <= cap) {
    // slim path: e precomputed, coalesced stream
    int p = beg;
    for (; p + 4 <= end; p += 4) {
      int s0 = srcs[p], s1 = srcs[p + 1], s2 = srcs[p + 2], s3 = srcs[p + 3];
      unsigned int e0 = epk[(size_t)(p + 0) * 64 + lane];
      unsigned int e1 = epk[(size_t)(p + 1) * 64 + lane];
      unsigned int e2 = epk[(size_t)(p + 2) * 64 + lane];
      unsigned int e3 = epk[(size_t)(p + 3) * 64 + lane];
      unsigned int z0 = zpk[(size_t)s0 * 64 + lane];
      unsigned int z1 = zpk[(size_t)s1 * 64 + lane];
      unsigned int z2 = zpk[(size_t)s2 * 64 + lane];
      unsigned int z3 = zpk[(size_t)s3 * 64 + lane];
      estep(e0, z0, t, d, a);
      estep(e1, z1, t, d, a);
      estep(e2, z2, t, d, a);
      estep(e3, z3, t, d, a);
    }
    for (; p < end; ++p) {
      unsigned int e = epk[(size_t)p * 64 + lane];
      unsigned int z = zpk[(size_t)srcs[p] * 64 + lane];
      estep(e, z, t, d, a);
    }
  } else {
    // recompute path
    f32x2 ew[PEIN_];
#pragma unroll
    for (int k = 0; k < PEIN_; ++k)
      ew[k] = (f32x2){edge_W[k * HH + lane], edge_W[k * HH + lane + 64]};
    f32x2 eb = (f32x2){edge_b[lane], edge_b[lane + 64]};
    int p = beg;
    for (; p + 4 <= end; p += 4) {
      int2 se0 = csr[p + 0];
      int2 se1 = csr[p + 1];
      int2 se2 = csr[p + 2];
      int2 se3 = csr[p + 3];
      const float4* e0p = (const float4*)(edge_attr + (size_t)se0.y * PEIN_);
      const float4* e1p = (const float4*)(edge_attr + (size_t)se1.y * PEIN_);
      const float4* e2p = (const float4*)(edge_attr + (size_t)se2.y * PEIN_);
      const float4* e3p = (const float4*)(edge_attr + (size_t)se3.y * PEIN_);
      float4 A0 = e0p[0], B0 = e0p[1];
      float4 A1 = e1p[0], B1 = e1p[1];
      float4 A2 = e2p[0], B2 = e2p[1];
      float4 A3 = e3p[0], B3 = e3p[1];
      unsigned int z0 = zpk[(size_t)se0.x * 64 + lane];
      unsigned int z1 = zpk[(size_t)se1.x * 64 + lane];
      unsigned int z2 = zpk[(size_t)se2.x * 64 + lane];
      unsigned int z3 = zpk[(size_t)se3.x * 64 + lane];
      edge_step(A0, B0, z0, ew, eb, t, d, a);
      edge_step(A1, B1, z1, ew, eb, t, d, a);
      edge_step(A2, B2, z2, ew, eb, t, d, a);
      edge_step(A3, B3, z3, ew, eb, t, d, a);
    }
    for (; p < end; ++p) {
      int2 se = csr[p];
      const float4* ep = (const float4*)(edge_attr + (size_t)se.y * PEIN_);
      float4 A = ep[0], B = ep[1];
      unsigned int zp = zpk[(size_t)se.x * 64 + lane];
      edge_step(A, B, zp, ew, eb, t, d, a);
    }
  }

  float agg0 = (d.x > 0.f) ? a.x / fmaxf(d.x, EPSM) : 0.f;
  float agg1 = (d.y > 0.f) ? a.y / fmaxf(d.y, EPSM) : 0.f;
  upk[(size_t)n * 64 + lane] = packbf(agg0 + bflo(zs), agg1 + bfhi(zs));
}

// ---------------- weight prep ----------------

__global__ __launch_bounds__(256) void prep_weights_kernel(
    const float* __restrict__ W1, const float* __restrict__ W2,
    unsigned short* __restrict__ W1Tp, unsigned short* __restrict__ W2T) {
  int idx = blockIdx.x * 256 + threadIdx.x;
  if (idx >= LAYERS_ * 256 * 128) return;
  int l = idx >> 15, r = idx & 32767;
  int n = r >> 7, p = r & 127;
  int k = (p >> 1) + ((p & 1) << 6);
  W1Tp[idx] = f2bf(W1[(l << 15) + k * 256 + n]);
  int c = r >> 8, kk = r & 255;
  W2T[idx] = f2bf(W2[(l << 15) + kk * 128 + c]);
}

// ---------------- node encoder (packed bf16 only) ----------------

__global__ __launch_bounds__(64) void node_enc_kernel(const float* __restrict__ x,
                                                      const float* __restrict__ W,
                                                      const float* __restrict__ b,
                                                      unsigned int* __restrict__ hbp) {
  __shared__ float xs[8 * PIN_];
  int f = threadIdx.x;
  float w0[PIN_], w1[PIN_];
#pragma unroll
  for (int k = 0; k < PIN_; ++k) {
    w0[k] = W[k * HH + f];
    w1[k] = W[k * HH + f + 64];
  }
  float b0 = b[f], b1c = b[f + 64];
  int base = blockIdx.x * 8;
  xs[f] = x[(size_t)base * PIN_ + f];
  xs[f + 64] = x[(size_t)base * PIN_ + f + 64];
  __syncthreads();
#pragma unroll
  for (int r = 0; r < 8; ++r) {
    float a0 = b0, a1 = b1c;
#pragma unroll
    for (int k = 0; k < PIN_; ++k) {
      a0 = fmaf(xs[r * PIN_ + k], w0[k], a0);
      a1 = fmaf(xs[r * PIN_ + k], w1[k], a1);
    }
    hbp[(size_t)(base + r) * 64 + f] = packbf(a0, a1);
  }
}

// ---------------- fused MLP (operand-swapped MFMA: lane owns ROW slices) ----------

__global__ __launch_bounds__(256) void mlp_fused_kernel(
    const unsigned int* __restrict__ upk,
    const unsigned short* __restrict__ W1Tp,  // [256][128] pair-packed K
    const float* __restrict__ b1v, const float* __restrict__ g1v,
    const float* __restrict__ be1v,
    const unsigned short* __restrict__ W2T,   // [128][256]
    const float* __restrict__ b2v,
    const float* __restrict__ res,            // nullptr on layer 0
    const float* __restrict__ ngv, const float* __restrict__ nbv,
    float* __restrict__ hout, unsigned int* __restrict__ zbp) {
  __shared__ __align__(16) unsigned short Tlds[4 * 4096];  // 32 KB
  int wv = threadIdx.x >> 6, lane = threadIdx.x & 63;
  int gw = blockIdx.x * 4 + wv;
  if (gw >= NN / 16) return;
  int row0 = gw * 16;
  int l15 = lane & 15, qg = lane >> 4;
  int co = 4 * qg;
  int sx = (l15 & 7) << 3;
  unsigned short* tl = Tlds + wv * 4096;

  const unsigned short* ub =
      (const unsigned short*)upk + (size_t)(row0 + l15) * HH + qg * 8;
  bf16x8 ufr[4];
#pragma unroll
  for (int kb = 0; kb < 4; ++kb) ufr[kb] = *(const bf16x8*)(ub + kb * 32);
  f32x4 acc1[16];
#pragma unroll
  for (int nb = 0; nb < 16; ++nb) acc1[nb] = (f32x4){0.f, 0.f, 0.f, 0.f};
#pragma unroll
  for (int nb = 0; nb < 16; ++nb) {
#pragma unroll
    for (int kb = 0; kb < 4; ++kb) {
      bf16x8 wf = *(const bf16x8*)(W1Tp + (size_t)(nb * 16 + l15) * HH + kb * 32 + qg * 8);
      acc1[nb] = __builtin_amdgcn_mfma_f32_16x16x32_bf16(wf, ufr[kb], acc1[nb], 0, 0, 0);
    }
  }

  float sum1 = 0.f;
#pragma unroll
  for (int nb = 0; nb < 16; ++nb) {
    float4 bq = *(const float4*)(b1v + nb * 16 + co);
    acc1[nb][0] += bq.x; acc1[nb][1] += bq.y;
    acc1[nb][2] += bq.z; acc1[nb][3] += bq.w;
    sum1 += acc1[nb][0] + acc1[nb][1] + acc1[nb][2] + acc1[nb][3];
  }
  sum1 += __shfl_xor(sum1, 16, 64);
  sum1 += __shfl_xor(sum1, 32, 64);
  float mu1 = sum1 * (1.f / 256.f);
  float sq1 = 0.f;
#pragma unroll
  for (int nb = 0; nb < 16; ++nb)
#pragma unroll
    for (int i = 0; i < 4; ++i) {
      float dd = acc1[nb][i] - mu1;
      sq1 = fmaf(dd, dd, sq1);
    }
  sq1 += __shfl_xor(sq1, 16, 64);
  sq1 += __shfl_xor(sq1, 32, 64);
  float rstd1 = rsqrtf(sq1 * (1.f / 256.f) + 1e-5f);
#pragma unroll
  for (int nb = 0; nb < 16; ++nb) {
    float4 gq = *(const float4*)(g1v + nb * 16 + co);
    float4 eq = *(const float4*)(be1v + nb * 16 + co);
    float t0 = fmaxf(fmaf((acc1[nb][0] - mu1) * rstd1, gq.x, eq.x), 0.f);
    float t1 = fmaxf(fmaf((acc1[nb][1] - mu1) * rstd1, gq.y, eq.y), 0.f);
    float t2 = fmaxf(fmaf((acc1[nb][2] - mu1) * rstd1, gq.z, eq.z), 0.f);
    float t3 = fmaxf(fmaf((acc1[nb][3] - mu1) * rstd1, gq.w, eq.w), 0.f);
    int ad = l15 * 256 + ((nb * 16 + co) ^ sx);
    *(uint2*)(tl + ad) = make_uint2(packbf(t0, t1), packbf(t2, t3));
  }

  f32x4 acc2[8];
#pragma unroll
  for (int nc = 0; nc < 8; ++nc) acc2[nc] = (f32x4){0.f, 0.f, 0.f, 0.f};
#pragma unroll
  for (int kb = 0; kb < 8; ++kb) {
    bf16x8 tf = *(const bf16x8*)(tl + l15 * 256 + ((kb * 32 + qg * 8) ^ sx));
#pragma unroll
    for (int nc = 0; nc < 8; ++nc) {
      bf16x8 wf = *(const bf16x8*)(W2T + (size_t)(nc * 16 + l15) * 256 + kb * 32 + qg * 8);
      acc2[nc] = __builtin_amdgcn_mfma_f32_16x16x32_bf16(wf, tf, acc2[nc], 0, 0, 0);
    }
  }

  size_t rb = (size_t)(row0 + l15) * HH;
  float sum2 = 0.f;
#pragma unroll
  for (int nc = 0; nc < 8; ++nc) {
    float4 bq = *(const float4*)(b2v + nc * 16 + co);
    acc2[nc][0] += bq.x; acc2[nc][1] += bq.y;
    acc2[nc][2] += bq.z; acc2[nc][3] += bq.w;
    if (res) {
      float4 rq = *(const float4*)(res + rb + nc * 16 + co);
      acc2[nc][0] += rq.x; acc2[nc][1] += rq.y;
      acc2[nc][2] += rq.z; acc2[nc][3] += rq.w;
    }
    *(float4*)(hout + rb + nc * 16 + co) =
        make_float4(acc2[nc][0], acc2[nc][1], acc2[nc][2], acc2[nc][3]);
    sum2 += acc2[nc][0] + acc2[nc][1] + acc2[nc][2] + acc2[nc][3];
  }
  sum2 += __shfl_xor(sum2, 16, 64);
  sum2 += __shfl_xor(sum2, 32, 64);
  float mu2 = sum2 * (1.f / 128.f);
  float sq2 = 0.f;
#pragma unroll
  for (int nc = 0; nc < 8; ++nc)
#pragma unroll
    for (int i = 0; i < 4; ++i) {
      float dd = acc2[nc][i] - mu2;
      sq2 = fmaf(dd, dd, sq2);
    }
  sq2 += __shfl_xor(sq2, 16, 64);
  sq2 += __shfl_xor(sq2, 32, 64);
  float rstd2 = rsqrtf(sq2 * (1.f / 128.f) + 1e-5f);
#pragma unroll
  for (int nc = 0; nc < 8; ++nc) {
    float4 gq = *(const float4*)(ngv + nc * 16 + co);
    float4 eq = *(const float4*)(nbv + nc * 16 + co);
    acc2[nc][0] = fmaxf(fmaf((acc2[nc][0] - mu2) * rstd2, gq.x, eq.x), 0.f);
    acc2[nc][1] = fmaxf(fmaf((acc2[nc][1] - mu2) * rstd2, gq.y, eq.y), 0.f);
    acc2[nc][2] = fmaxf(fmaf((acc2[nc][2] - mu2) * rstd2, gq.z, eq.z), 0.f);
    acc2[nc][3] = fmaxf(fmaf((acc2[nc][3] - mu2) * rstd2, gq.w, eq.w), 0.f);
  }
#pragma unroll
  for (int nc = 0; nc < 4; ++nc) {
    *(uint4*)(zbp + (size_t)(row0 + l15) * 64 + nc * 16 + co) =
        make_uint4(packbf(acc2[nc][0], acc2[nc + 4][0]),
                   packbf(acc2[nc][1], acc2[nc + 4][1]),
                   packbf(acc2[nc][2], acc2[nc + 4][2]),
                   packbf(acc2[nc][3], acc2[nc + 4][3]));
  }
}

// ---------------- output head (reads packed bf16 z) ----------------

__global__ __launch_bounds__(256) void out_head_kernel(const unsigned int* __restrict__ zbp,
                                                       const float* __restrict__ W,
                                                       const float* __restrict__ b,
                                                       float* __restrict__ out) {
  __shared__ float Wl[HH * POUT_];
  int t = threadIdx.x;
  for (int i = t; i < HH * POUT_; i += 256) Wl[i] = W[i];
  __syncthreads();
  int n = blockIdx.x * 32 + (t >> 3);
  int p = t & 7;
  if (n >= NN) return;
  float acc = b[p];
  const unsigned int* zr = zbp + (size_t)n * 64;
#pragma unroll 8
  for (int f = 0; f < 64; ++f) {
    unsigned int zp = zr[f];
    acc = fmaf(__uint_as_float(zp << 16), Wl[f * POUT_ + p], acc);
    acc = fmaf(__uint_as_float(zp & 0xFFFF0000u), Wl[(f + 64) * POUT_ + p], acc);
  }
  out[(size_t)n * POUT_ + p] = acc;
}

// ---------------- launch ----------------

extern "C" void kernel_launch(void* const* d_in, const int* in_sizes, int n_in,
                              void* d_out, int out_size, void* d_ws, size_t ws_size,
                              hipStream_t stream) {
  const float* x = (const float*)d_in[0];
  const float* edge_attr = (const float*)d_in[1];
  const int* edge_index = (const int*)d_in[2];
  const float* node_W = (const float*)d_in[3];
  const float* node_b = (const float*)d_in[4];
  const float* edge_W = (const float*)d_in[5];
  const float* edge_b = (const float*)d_in[6];
  const float* W1 = (const float*)d_in[7];
  const float* b1 = (const float*)d_in[8];
  const float* g1 = (const float*)d_in[9];
  const float* be1 = (const float*)d_in[10];
  const float* W2 = (const float*)d_in[11];
  const float* b2 = (const float*)d_in[12];
  const float* t_all = (const float*)d_in[13];
  const float* ng = (const float*)d_in[14];
  const float* nb = (const float*)d_in[15];
  const float* out_W = (const float*)d_in[16];
  const float* out_b = (const float*)d_in[17];

  const int* src = edge_index;
  const int* dst = edge_index + NE;

  char* w = (char*)d_ws;
  float* h = (float*)w;                                     // 25.6 MB (f32 residual)
  unsigned int* upk = (unsigned int*)(w + 25600000);        // 12.8 MB
  unsigned int* zbp = (unsigned int*)(w + 38400000);        // 12.8 MB (also hbp)
  int* deg = (int*)(w + 51200000);                          // 204,800
  int* row_ptr = (int*)(w + 51404800);                      // 204,800
  int* cursor = (int*)(w + 51609600);                       // 204,800
  int2* csr = (int2*)(w + 51814400);                        // 6.4 MB
  unsigned short* W1Tp = (unsigned short*)(w + 58214400);   // 262,144
  unsigned short* W2Tb = (unsigned short*)(w + 58476544);   // 262,144
  int* srcs = (int*)(w + 58738688);                         // 3,200,512
  unsigned int* epk = (unsigned int*)(w + 61939200);        // up to 204.8 MB

  long long avail = (long long)ws_size - 61939200ll;
  int cap = 0;
  if (avail > 0) {
    long long c = avail / 256;
    cap = (int)(c < (long long)NE ? c : (long long)NE);
  }

  hipMemsetAsync(deg, 0, NN * sizeof(int), stream);
  count_deg_kernel<<<(NE + 255) / 256, 256, 0, stream>>>(dst, deg);
  scan_kernel<<<1, 1024, 0, stream>>>(deg, row_ptr, cursor, NN);
  scatter_kernel<<<(NE + 255) / 256, 256, 0, stream>>>(src, dst, cursor, csr, srcs);
  if (cap > 0)
    edge_enc_kernel<<<(cap + 3) / 4, 256, 0, stream>>>(csr, edge_attr, edge_W, edge_b,
                                                       cap, epk);
  prep_weights_kernel<<<512, 256, 0, stream>>>(W1, W2, W1Tp, W2Tb);
  node_enc_kernel<<<NN / 8, 64, 0, stream>>>(x, node_W, node_b, zbp);

  const int mlp_blocks = (NN / 16 + 3) / 4;  // 782
  for (int i = 0; i < LAYERS_; ++i) {
    aggregate_hyb_kernel<<<NN / 4, 256, 0, stream>>>(row_ptr, csr, srcs, epk, cap,
                                                     edge_attr, edge_W, edge_b,
                                                     zbp, t_all, i, upk);
    int zn = (i + 1) % LAYERS_;  // norm params for the NEXT consumer (ng[0] on last)
    mlp_fused_kernel<<<mlp_blocks, 256, 0, stream>>>(
        upk, W1Tp + (size_t)i * 32768, b1 + i * 256, g1 + i * 256, be1 + i * 256,
        W2Tb + (size_t)i * 32768, b2 + i * HH,
        (i == 0) ? nullptr : h,
        ng + zn * HH, nb + zn * HH, h, zbp);
  }
  out_head_kernel<<<(NN + 31) / 32, 256, 0, stream>>>(zbp, out_W, out_b, (float*)d_out);
}

// Round 15
// 899.033 us; speedup vs baseline: 1.1646x; 1.1646x over previous
//
#include <hip/hip_runtime.h>
#include <hip/hip_bf16.h>

#define NN 50000
#define NE 800000
#define HH 128
#define PIN_ 16
#define PEIN_ 8
#define POUT_ 8
#define LAYERS_ 4
#define EPSM 1e-7f

typedef __bf16 bf16x8 __attribute__((ext_vector_type(8)));
typedef float f32x4 __attribute__((ext_vector_type(4)));
typedef float f32x2 __attribute__((ext_vector_type(2)));

__device__ inline unsigned short f2bf(float f) {
  unsigned int u = __float_as_uint(f);
  u += 0x7FFFu + ((u >> 16) & 1u);  // RNE
  return (unsigned short)(u >> 16);
}
__device__ inline unsigned int packbf(float lo, float hi) {
  return (unsigned int)f2bf(lo) | ((unsigned int)f2bf(hi) << 16);
}
__device__ inline float bflo(unsigned int p) { return __uint_as_float(p << 16); }
__device__ inline float bfhi(unsigned int p) { return __uint_as_float(p & 0xFFFF0000u); }
__device__ inline f32x2 unpk(unsigned int p) {
  return (f32x2){__uint_as_float(p << 16), __uint_as_float(p & 0xFFFF0000u)};
}

// ---------------- CSR build (single atomic pass) ----------------
// pass 1: count degrees AND record each edge's within-node rank k.
// pass 2 (after scan): place at row_ptr[dst]+k — no atomics.

__global__ void count_deg_kernel(const int* __restrict__ dst, int* __restrict__ deg,
                                 int* __restrict__ kof) {
  int i = blockIdx.x * blockDim.x + threadIdx.x;
  if (i < NE) kof[i] = atomicAdd(&deg[dst[i]], 1);
}

__global__ __launch_bounds__(1024) void scan_kernel(const int* __restrict__ deg,
                                                    int* __restrict__ row_ptr, int n) {
  __shared__ int wsum[16];
  __shared__ int carry_s;
  int t = threadIdx.x;
  int lane = t & 63, wv = t >> 6;
  if (t == 0) carry_s = 0;
  __syncthreads();
  for (int base = 0; base < n; base += 1024) {
    int i = base + t;
    int v = (i < n) ? deg[i] : 0;
    int x = v;
#pragma unroll
    for (int off = 1; off < 64; off <<= 1) {
      int y = __shfl_up(x, off, 64);
      if (lane >= off) x += y;
    }
    if (lane == 63) wsum[wv] = x;
    __syncthreads();
    if (wv == 0 && lane < 16) {
      int s = wsum[lane];
#pragma unroll
      for (int off = 1; off < 16; off <<= 1) {
        int y = __shfl_up(s, off, 16);
        if (lane >= off) s += y;
      }
      wsum[lane] = s;
    }
    __syncthreads();
    int waveExcl = (wv > 0) ? wsum[wv - 1] : 0;
    int carry = carry_s;
    int excl = carry + waveExcl + x - v;
    if (i < n) row_ptr[i] = excl;
    __syncthreads();
    if (t == 1023) carry_s = carry + wsum[15];
    __syncthreads();
  }
  if (t == 0) row_ptr[n] = carry_s;
}

__global__ void place_kernel(const int* __restrict__ src, const int* __restrict__ dst,
                             const int* __restrict__ row_ptr, const int* __restrict__ kof,
                             int2* __restrict__ csr) {
  int i = blockIdx.x * blockDim.x + threadIdx.x;
  if (i < NE) {
    int pos = row_ptr[dst[i]] + kof[i];
    csr[pos] = make_int2(src[i], i);
  }
}

// ---------------- softmax aggregation (recompute e, pk-f32 math) -------------

__device__ __forceinline__ void edge_step(float4 A, float4 B, unsigned int zp,
                                          const f32x2* ew, f32x2 eb, float t,
                                          f32x2& d, f32x2& a) {
  f32x2 acc = eb;
  acc = __builtin_elementwise_fma((f32x2){A.x, A.x}, ew[0], acc);
  acc = __builtin_elementwise_fma((f32x2){A.y, A.y}, ew[1], acc);
  acc = __builtin_elementwise_fma((f32x2){A.z, A.z}, ew[2], acc);
  acc = __builtin_elementwise_fma((f32x2){A.w, A.w}, ew[3], acc);
  acc = __builtin_elementwise_fma((f32x2){B.x, B.x}, ew[4], acc);
  acc = __builtin_elementwise_fma((f32x2){B.y, B.y}, ew[5], acc);
  acc = __builtin_elementwise_fma((f32x2){B.z, B.z}, ew[6], acc);
  acc = __builtin_elementwise_fma((f32x2){B.w, B.w}, ew[7], acc);
  f32x2 e;
  e.x = __builtin_amdgcn_rcpf(1.f + __expf(-acc.x));
  e.y = __builtin_amdgcn_rcpf(1.f + __expf(-acc.y));
  f32x2 msg = unpk(zp) + e;
  msg = __builtin_elementwise_max(msg, (f32x2){0.f, 0.f});
  msg += (f32x2){EPSM, EPSM};
  f32x2 s = msg * t;
  f32x2 w;
  w.x = __expf(s.x);
  w.y = __expf(s.y);
  d += w;
  a = __builtin_elementwise_fma(msg, w, a);
}

__global__ __launch_bounds__(256) void aggregate_kernel(
    const int* __restrict__ row_ptr, const int2* __restrict__ csr,
    const float* __restrict__ edge_attr, const float* __restrict__ edge_W,
    const float* __restrict__ edge_b, const unsigned int* __restrict__ zpk,
    const float* __restrict__ t_all, int layer, unsigned int* __restrict__ upk) {
  int wv = threadIdx.x >> 6, lane = threadIdx.x & 63;
  int n = blockIdx.x * 4 + wv;
  if (n >= NN) return;
  f32x2 ew[PEIN_];
#pragma unroll
  for (int k = 0; k < PEIN_; ++k)
    ew[k] = (f32x2){edge_W[k * HH + lane], edge_W[k * HH + lane + 64]};
  f32x2 eb = (f32x2){edge_b[lane], edge_b[lane + 64]};
  float t = t_all[layer];
  int beg = row_ptr[n], end = row_ptr[n + 1];
  unsigned int zs = zpk[(size_t)n * 64 + lane];
  f32x2 d = {0.f, 0.f}, a = {0.f, 0.f};
  int p = beg;
  for (; p + 4 <= end; p += 4) {
    int2 se0 = csr[p + 0];
    int2 se1 = csr[p + 1];
    int2 se2 = csr[p + 2];
    int2 se3 = csr[p + 3];
    const float4* e0p = (const float4*)(edge_attr + (size_t)se0.y * PEIN_);
    const float4* e1p = (const float4*)(edge_attr + (size_t)se1.y * PEIN_);
    const float4* e2p = (const float4*)(edge_attr + (size_t)se2.y * PEIN_);
    const float4* e3p = (const float4*)(edge_attr + (size_t)se3.y * PEIN_);
    float4 A0 = e0p[0], B0 = e0p[1];
    float4 A1 = e1p[0], B1 = e1p[1];
    float4 A2 = e2p[0], B2 = e2p[1];
    float4 A3 = e3p[0], B3 = e3p[1];
    unsigned int z0 = zpk[(size_t)se0.x * 64 + lane];
    unsigned int z1 = zpk[(size_t)se1.x * 64 + lane];
    unsigned int z2 = zpk[(size_t)se2.x * 64 + lane];
    unsigned int z3 = zpk[(size_t)se3.x * 64 + lane];
    edge_step(A0, B0, z0, ew, eb, t, d, a);
    edge_step(A1, B1, z1, ew, eb, t, d, a);
    edge_step(A2, B2, z2, ew, eb, t, d, a);
    edge_step(A3, B3, z3, ew, eb, t, d, a);
  }
  for (; p < end; ++p) {
    int2 se = csr[p];
    const float4* ep = (const float4*)(edge_attr + (size_t)se.y * PEIN_);
    float4 A = ep[0], B = ep[1];
    unsigned int zp = zpk[(size_t)se.x * 64 + lane];
    edge_step(A, B, zp, ew, eb, t, d, a);
  }
  float agg0 = (d.x > 0.f) ? a.x / fmaxf(d.x, EPSM) : 0.f;
  float agg1 = (d.y > 0.f) ? a.y / fmaxf(d.y, EPSM) : 0.f;
  upk[(size_t)n * 64 + lane] = packbf(agg0 + bflo(zs), agg1 + bfhi(zs));
}

// ---------------- weight prep ----------------

__global__ __launch_bounds__(256) void prep_weights_kernel(
    const float* __restrict__ W1, const float* __restrict__ W2,
    unsigned short* __restrict__ W1Tp, unsigned short* __restrict__ W2T) {
  int idx = blockIdx.x * 256 + threadIdx.x;
  if (idx >= LAYERS_ * 256 * 128) return;
  int l = idx >> 15, r = idx & 32767;
  int n = r >> 7, p = r & 127;
  int k = (p >> 1) + ((p & 1) << 6);
  W1Tp[idx] = f2bf(W1[(l << 15) + k * 256 + n]);
  int c = r >> 8, kk = r & 255;
  W2T[idx] = f2bf(W2[(l << 15) + kk * 128 + c]);
}

// ---------------- node encoder (packed bf16 only) ----------------

__global__ __launch_bounds__(64) void node_enc_kernel(const float* __restrict__ x,
                                                      const float* __restrict__ W,
                                                      const float* __restrict__ b,
                                                      unsigned int* __restrict__ hbp) {
  __shared__ float xs[8 * PIN_];
  int f = threadIdx.x;
  float w0[PIN_], w1[PIN_];
#pragma unroll
  for (int k = 0; k < PIN_; ++k) {
    w0[k] = W[k * HH + f];
    w1[k] = W[k * HH + f + 64];
  }
  float b0 = b[f], b1c = b[f + 64];
  int base = blockIdx.x * 8;
  xs[f] = x[(size_t)base * PIN_ + f];
  xs[f + 64] = x[(size_t)base * PIN_ + f + 64];
  __syncthreads();
#pragma unroll
  for (int r = 0; r < 8; ++r) {
    float a0 = b0, a1 = b1c;
#pragma unroll
    for (int k = 0; k < PIN_; ++k) {
      a0 = fmaf(xs[r * PIN_ + k], w0[k], a0);
      a1 = fmaf(xs[r * PIN_ + k], w1[k], a1);
    }
    hbp[(size_t)(base + r) * 64 + f] = packbf(a0, a1);
  }
}

// ---------------- fused MLP (operand-swapped MFMA: lane owns ROW slices) ----------

__global__ __launch_bounds__(256) void mlp_fused_kernel(
    const unsigned int* __restrict__ upk,
    const unsigned short* __restrict__ W1Tp,  // [256][128] pair-packed K
    const float* __restrict__ b1v, const float* __restrict__ g1v,
    const float* __restrict__ be1v,
    const unsigned short* __restrict__ W2T,   // [128][256]
    const float* __restrict__ b2v,
    const float* __restrict__ res,            // nullptr on layer 0
    const float* __restrict__ ngv, const float* __restrict__ nbv,
    float* __restrict__ hout, unsigned int* __restrict__ zbp) {
  __shared__ __align__(16) unsigned short Tlds[4 * 4096];  // 32 KB
  int wv = threadIdx.x >> 6, lane = threadIdx.x & 63;
  int gw = blockIdx.x * 4 + wv;
  if (gw >= NN / 16) return;
  int row0 = gw * 16;
  int l15 = lane & 15, qg = lane >> 4;
  int co = 4 * qg;
  int sx = (l15 & 7) << 3;
  unsigned short* tl = Tlds + wv * 4096;

  const unsigned short* ub =
      (const unsigned short*)upk + (size_t)(row0 + l15) * HH + qg * 8;
  bf16x8 ufr[4];
#pragma unroll
  for (int kb = 0; kb < 4; ++kb) ufr[kb] = *(const bf16x8*)(ub + kb * 32);
  f32x4 acc1[16];
#pragma unroll
  for (int nb = 0; nb < 16; ++nb) acc1[nb] = (f32x4){0.f, 0.f, 0.f, 0.f};
#pragma unroll
  for (int nb = 0; nb < 16; ++nb) {
#pragma unroll
    for (int kb = 0; kb < 4; ++kb) {
      bf16x8 wf = *(const bf16x8*)(W1Tp + (size_t)(nb * 16 + l15) * HH + kb * 32 + qg * 8);
      acc1[nb] = __builtin_amdgcn_mfma_f32_16x16x32_bf16(wf, ufr[kb], acc1[nb], 0, 0, 0);
    }
  }

  float sum1 = 0.f;
#pragma unroll
  for (int nb = 0; nb < 16; ++nb) {
    float4 bq = *(const float4*)(b1v + nb * 16 + co);
    acc1[nb][0] += bq.x; acc1[nb][1] += bq.y;
    acc1[nb][2] += bq.z; acc1[nb][3] += bq.w;
    sum1 += acc1[nb][0] + acc1[nb][1] + acc1[nb][2] + acc1[nb][3];
  }
  sum1 += __shfl_xor(sum1, 16, 64);
  sum1 += __shfl_xor(sum1, 32, 64);
  float mu1 = sum1 * (1.f / 256.f);
  float sq1 = 0.f;
#pragma unroll
  for (int nb = 0; nb < 16; ++nb)
#pragma unroll
    for (int i = 0; i < 4; ++i) {
      float dd = acc1[nb][i] - mu1;
      sq1 = fmaf(dd, dd, sq1);
    }
  sq1 += __shfl_xor(sq1, 16, 64);
  sq1 += __shfl_xor(sq1, 32, 64);
  float rstd1 = rsqrtf(sq1 * (1.f / 256.f) + 1e-5f);
#pragma unroll
  for (int nb = 0; nb < 16; ++nb) {
    float4 gq = *(const float4*)(g1v + nb * 16 + co);
    float4 eq = *(const float4*)(be1v + nb * 16 + co);
    float t0 = fmaxf(fmaf((acc1[nb][0] - mu1) * rstd1, gq.x, eq.x), 0.f);
    float t1 = fmaxf(fmaf((acc1[nb][1] - mu1) * rstd1, gq.y, eq.y), 0.f);
    float t2 = fmaxf(fmaf((acc1[nb][2] - mu1) * rstd1, gq.z, eq.z), 0.f);
    float t3 = fmaxf(fmaf((acc1[nb][3] - mu1) * rstd1, gq.w, eq.w), 0.f);
    int ad = l15 * 256 + ((nb * 16 + co) ^ sx);
    *(uint2*)(tl + ad) = make_uint2(packbf(t0, t1), packbf(t2, t3));
  }

  f32x4 acc2[8];
#pragma unroll
  for (int nc = 0; nc < 8; ++nc) acc2[nc] = (f32x4){0.f, 0.f, 0.f, 0.f};
#pragma unroll
  for (int kb = 0; kb < 8; ++kb) {
    bf16x8 tf = *(const bf16x8*)(tl + l15 * 256 + ((kb * 32 + qg * 8) ^ sx));
#pragma unroll
    for (int nc = 0; nc < 8; ++nc) {
      bf16x8 wf = *(const bf16x8*)(W2T + (size_t)(nc * 16 + l15) * 256 + kb * 32 + qg * 8);
      acc2[nc] = __builtin_amdgcn_mfma_f32_16x16x32_bf16(wf, tf, acc2[nc], 0, 0, 0);
    }
  }

  size_t rb = (size_t)(row0 + l15) * HH;
  float sum2 = 0.f;
#pragma unroll
  for (int nc = 0; nc < 8; ++nc) {
    float4 bq = *(const float4*)(b2v + nc * 16 + co);
    acc2[nc][0] += bq.x; acc2[nc][1] += bq.y;
    acc2[nc][2] += bq.z; acc2[nc][3] += bq.w;
    if (res) {
      float4 rq = *(const float4*)(res + rb + nc * 16 + co);
      acc2[nc][0] += rq.x; acc2[nc][1] += rq.y;
      acc2[nc][2] += rq.z; acc2[nc][3] += rq.w;
    }
    *(float4*)(hout + rb + nc * 16 + co) =
        make_float4(acc2[nc][0], acc2[nc][1], acc2[nc][2], acc2[nc][3]);
    sum2 += acc2[nc][0] + acc2[nc][1] + acc2[nc][2] + acc2[nc][3];
  }
  sum2 += __shfl_xor(sum2, 16, 64);
  sum2 += __shfl_xor(sum2, 32, 64);
  float mu2 = sum2 * (1.f / 128.f);
  float sq2 = 0.f;
#pragma unroll
  for (int nc = 0; nc < 8; ++nc)
#pragma unroll
    for (int i = 0; i < 4; ++i) {
      float dd = acc2[nc][i] - mu2;
      sq2 = fmaf(dd, dd, sq2);
    }
  sq2 += __shfl_xor(sq2, 16, 64);
  sq2 += __shfl_xor(sq2, 32, 64);
  float rstd2 = rsqrtf(sq2 * (1.f / 128.f) + 1e-5f);
#pragma unroll
  for (int nc = 0; nc < 8; ++nc) {
    float4 gq = *(const float4*)(ngv + nc * 16 + co);
    float4 eq = *(const float4*)(nbv + nc * 16 + co);
    acc2[nc][0] = fmaxf(fmaf((acc2[nc][0] - mu2) * rstd2, gq.x, eq.x), 0.f);
    acc2[nc][1] = fmaxf(fmaf((acc2[nc][1] - mu2) * rstd2, gq.y, eq.y), 0.f);
    acc2[nc][2] = fmaxf(fmaf((acc2[nc][2] - mu2) * rstd2, gq.z, eq.z), 0.f);
    acc2[nc][3] = fmaxf(fmaf((acc2[nc][3] - mu2) * rstd2, gq.w, eq.w), 0.f);
  }
#pragma unroll
  for (int nc = 0; nc < 4; ++nc) {
    *(uint4*)(zbp + (size_t)(row0 + l15) * 64 + nc * 16 + co) =
        make_uint4(packbf(acc2[nc][0], acc2[nc + 4][0]),
                   packbf(acc2[nc][1], acc2[nc + 4][1]),
                   packbf(acc2[nc][2], acc2[nc + 4][2]),
                   packbf(acc2[nc][3], acc2[nc + 4][3]));
  }
}

// ---------------- output head (reads packed bf16 z) ----------------

__global__ __launch_bounds__(256) void out_head_kernel(const unsigned int* __restrict__ zbp,
                                                       const float* __restrict__ W,
                                                       const float* __restrict__ b,
                                                       float* __restrict__ out) {
  __shared__ float Wl[HH * POUT_];
  int t = threadIdx.x;
  for (int i = t; i < HH * POUT_; i += 256) Wl[i] = W[i];
  __syncthreads();
  int n = blockIdx.x * 32 + (t >> 3);
  int p = t & 7;
  if (n >= NN) return;
  float acc = b[p];
  const unsigned int* zr = zbp + (size_t)n * 64;
#pragma unroll 8
  for (int f = 0; f < 64; ++f) {
    unsigned int zp = zr[f];
    acc = fmaf(__uint_as_float(zp << 16), Wl[f * POUT_ + p], acc);
    acc = fmaf(__uint_as_float(zp & 0xFFFF0000u), Wl[(f + 64) * POUT_ + p], acc);
  }
  out[(size_t)n * POUT_ + p] = acc;
}

// ---------------- launch ----------------

extern "C" void kernel_launch(void* const* d_in, const int* in_sizes, int n_in,
                              void* d_out, int out_size, void* d_ws, size_t ws_size,
                              hipStream_t stream) {
  const float* x = (const float*)d_in[0];
  const float* edge_attr = (const float*)d_in[1];
  const int* edge_index = (const int*)d_in[2];
  const float* node_W = (const float*)d_in[3];
  const float* node_b = (const float*)d_in[4];
  const float* edge_W = (const float*)d_in[5];
  const float* edge_b = (const float*)d_in[6];
  const float* W1 = (const float*)d_in[7];
  const float* b1 = (const float*)d_in[8];
  const float* g1 = (const float*)d_in[9];
  const float* be1 = (const float*)d_in[10];
  const float* W2 = (const float*)d_in[11];
  const float* b2 = (const float*)d_in[12];
  const float* t_all = (const float*)d_in[13];
  const float* ng = (const float*)d_in[14];
  const float* nb = (const float*)d_in[15];
  const float* out_W = (const float*)d_in[16];
  const float* out_b = (const float*)d_in[17];

  const int* src = edge_index;
  const int* dst = edge_index + NE;

  char* w = (char*)d_ws;
  float* h = (float*)w;                                     // 25.6 MB (f32 residual)
  unsigned int* upk = (unsigned int*)(w + 25600000);        // 12.8 MB
  unsigned int* zbp = (unsigned int*)(w + 38400000);        // 12.8 MB (also hbp)
  int* deg = (int*)(w + 51200000);                          // 204,800
  int* row_ptr = (int*)(w + 51404800);                      // 204,800
  int2* csr = (int2*)(w + 51609600);                        // 6.4 MB
  unsigned short* W1Tp = (unsigned short*)(w + 58009600);   // 262,144
  unsigned short* W2Tb = (unsigned short*)(w + 58271744);   // 262,144
  int* kof = (int*)(w + 58533888);                          // 3.2 MB -> ends ~61.7 MB

  hipMemsetAsync(deg, 0, NN * sizeof(int), stream);
  count_deg_kernel<<<(NE + 255) / 256, 256, 0, stream>>>(dst, deg, kof);
  scan_kernel<<<1, 1024, 0, stream>>>(deg, row_ptr, NN);
  place_kernel<<<(NE + 255) / 256, 256, 0, stream>>>(src, dst, row_ptr, kof, csr);
  prep_weights_kernel<<<512, 256, 0, stream>>>(W1, W2, W1Tp, W2Tb);
  node_enc_kernel<<<NN / 8, 64, 0, stream>>>(x, node_W, node_b, zbp);

  const int mlp_blocks = (NN / 16 + 3) / 4;  // 782
  for (int i = 0; i < LAYERS_; ++i) {
    aggregate_kernel<<<NN / 4, 256, 0, stream>>>(row_ptr, csr, edge_attr, edge_W,
                                                 edge_b, zbp, t_all, i, upk);
    int zn = (i + 1) % LAYERS_;  // norm params for the NEXT consumer (ng[0] on last)
    mlp_fused_kernel<<<mlp_blocks, 256, 0, stream>>>(
        upk, W1Tp + (size_t)i * 32768, b1 + i * 256, g1 + i * 256, be1 + i * 256,
        W2Tb + (size_t)i * 32768, b2 + i * HH,
        (i == 0) ? nullptr : h,
        ng + zn * HH, nb + zn * HH, h, zbp);
  }
  out_head_kernel<<<(NN + 31) / 32, 256, 0, stream>>>(zbp, out_W, out_b, (float*)d_out);
}